// Round 12
// baseline (198.949 us; speedup 1.0000x reference)
//
#include <hip/hip_runtime.h>
#include <hip/hip_bf16.h>

#define SEQ_LEN 2048
#define NBATCH 2
#define DM 1024
#define NH 16
#define HD 64
#define NR (NBATCH * SEQ_LEN)  // 4096 rows
#define NQKV (3 * DM)          // 3072 fused QKV cols
#define LDQK 2048              // QK buffer leading dim (Q cols 0..1023, K 1024..2047)

typedef __attribute__((ext_vector_type(8))) short bf16x8;
typedef __attribute__((ext_vector_type(4))) float f32x4;
typedef __attribute__((ext_vector_type(16))) float f32x16;

__device__ __forceinline__ short f2b(float f) {
    __hip_bfloat16 h = __float2bfloat16(f);
    return *reinterpret_cast<short*>(&h);
}

// async global->LDS 16B copy
__device__ __forceinline__ void gload_lds16(const void* g, void* l) {
    __builtin_amdgcn_global_load_lds(
        (const __attribute__((address_space(1))) unsigned int*)g,
        (__attribute__((address_space(3))) unsigned int*)l, 16, 0, 0);
}

// ---------------------------------------------------------------------------
// Fused fp32->bf16 conversion for all 5 inputs in one launch.
// ---------------------------------------------------------------------------
__global__ __launch_bounds__(256) void cvt_all(
    const float* __restrict__ x,  const float* __restrict__ wq,
    const float* __restrict__ wk, const float* __restrict__ wv,
    const float* __restrict__ wo,
    __hip_bfloat16* __restrict__ xb, __hip_bfloat16* __restrict__ wqkvb,
    __hip_bfloat16* __restrict__ wob) {
    int id = blockIdx.x;
    const float* src; __hip_bfloat16* dst;
    if (id < 4096) { src = x + (size_t)id * 1024; dst = xb + (size_t)id * 1024; }
    else {
        int k = id - 4096, seg = k >> 10;
        size_t off = (size_t)(k & 1023) * 1024;
        if      (seg == 0) { src = wq + off; dst = wqkvb + off; }
        else if (seg == 1) { src = wk + off; dst = wqkvb + (1u << 20) + off; }
        else if (seg == 2) { src = wv + off; dst = wqkvb + (2u << 20) + off; }
        else               { src = wo + off; dst = wob + off; }
    }
    int i = threadIdx.x * 4;
    float4 v = *(const float4*)(src + i);
    dst[i + 0] = __float2bfloat16(v.x);
    dst[i + 1] = __float2bfloat16(v.y);
    dst[i + 2] = __float2bfloat16(v.z);
    dst[i + 3] = __float2bfloat16(v.w);
}

// ---------------------------------------------------------------------------
// gemm256_qkv: 256x256 8-phase dual-barrier counted-vmcnt GEMM with fused
// RoPE + V-transpose. (Unchanged from round 8 — passing.)
// ---------------------------------------------------------------------------
__global__ __launch_bounds__(512) void gemm256_qkv(
    const __hip_bfloat16* __restrict__ A,
    const __hip_bfloat16* __restrict__ B,
    __hip_bfloat16* __restrict__ C,
    __hip_bfloat16* __restrict__ Vtg,
    const int* __restrict__ pos) {
    __shared__ __hip_bfloat16 As[2][2][64 * 128];  // [buf][hm][128 rows x 64 cols]
    __shared__ __hip_bfloat16 Bs[2][2][64 * 128];  // [buf][hn][128 rows x 64 cols]

    const int t    = threadIdx.x;
    const int wave = t >> 6;        // 0..7
    const int wm   = wave >> 2;     // 0..1 (M half)
    const int wn   = wave & 3;      // 0..3 (N quarter)
    const int lane = t & 63;
    const int quad = lane >> 4;
    const int l16  = lane & 15;
    const int K    = DM;            // 1024
    const int NT   = K >> 6;        // 16 K-tiles
    const int NI   = K >> 7;        // 8 iterations

    // XCD-chunked bijective decode (192 blocks, 24/XCD)
    const int wg = (blockIdx.x & 7) * 24 + (blockIdx.x >> 3);
    const int bx = wg & 15;         // M/256 = 16
    const int by = wg >> 4;         // NQKV/256 = 12
    const int m0 = bx * 256, n0 = by * 256;

    const int  t16  = t * 16;
    const int  scx8 = ((t & 7) ^ ((t >> 3) & 7)) * 8;
    const int  srA  = t >> 3;             // A region row (L=0)
    const int  gB   = (t >> 8) & 1;       // B group for L=0 (L=1 adds 2)
    const int  rB   = (t >> 3) & 31;      // B row within group

#define STAGE_A(BUF, HM, TT)                                                    \
    {                                                                           \
        const __hip_bfloat16* _s =                                              \
            A + (size_t)(m0 + (HM) * 64 + srA) * K + (TT) * 64 + scx8;          \
        gload_lds16(_s,               (char*)As[BUF][HM] + t16);                \
        gload_lds16(_s + (size_t)128 * K, (char*)As[BUF][HM] + t16 + 8192);     \
    }
#define STAGE_B(BUF, HN, TT)                                                    \
    {                                                                           \
        const __hip_bfloat16* _s =                                              \
            B + (size_t)(n0 + gB * 64 + (HN) * 32 + rB) * K + (TT) * 64 + scx8; \
        gload_lds16(_s,               (char*)Bs[BUF][HN] + t16);                \
        gload_lds16(_s + (size_t)128 * K, (char*)Bs[BUF][HN] + t16 + 8192);     \
    }
#define LDA(BUF, HM, AF)                                                        \
    _Pragma("unroll") for (int rb = 0; rb < 4; rb++)                            \
    _Pragma("unroll") for (int kk = 0; kk < 2; kk++)                            \
        AF[rb][kk] = *(const bf16x8*)((const char*)As[BUF][HM] +                \
            (wm * 64 + rb * 16 + l16) * 128 + (((kk * 4 + quad) ^ (l16 & 7)) << 4));
#define LDB(BUF, HN, BF)                                                        \
    _Pragma("unroll") for (int cb = 0; cb < 2; cb++)                            \
    _Pragma("unroll") for (int kk = 0; kk < 2; kk++)                            \
        BF[cb][kk] = *(const bf16x8*)((const char*)Bs[BUF][HN] +                \
            (wn * 32 + cb * 16 + l16) * 128 + (((kk * 4 + quad) ^ (l16 & 7)) << 4));
#define MM(HM, HN, AF, BF)                                                      \
    {                                                                           \
        __builtin_amdgcn_s_setprio(1);                                          \
        _Pragma("unroll") for (int rb = 0; rb < 4; rb++)                        \
        _Pragma("unroll") for (int cb = 0; cb < 2; cb++) {                      \
            acc[HM][HN][rb][cb] = __builtin_amdgcn_mfma_f32_16x16x32_bf16(      \
                AF[rb][0], BF[cb][0], acc[HM][HN][rb][cb], 0, 0, 0);            \
            acc[HM][HN][rb][cb] = __builtin_amdgcn_mfma_f32_16x16x32_bf16(      \
                AF[rb][1], BF[cb][1], acc[HM][HN][rb][cb], 0, 0, 0);            \
        }                                                                       \
        __builtin_amdgcn_s_setprio(0);                                          \
    }
#define VM0 asm volatile("s_waitcnt vmcnt(0)" ::: "memory")
#define VM4 asm volatile("s_waitcnt vmcnt(4)" ::: "memory")
#define VM6 asm volatile("s_waitcnt vmcnt(6)" ::: "memory")
#define LGKM0 asm volatile("s_waitcnt lgkmcnt(0)" ::: "memory")
#define SCHED0 __builtin_amdgcn_sched_barrier(0)
#define BARR __builtin_amdgcn_s_barrier()
#define GATE_A SCHED0; BARR; LGKM0; SCHED0

    f32x4 acc[2][2][4][2];
#pragma unroll
    for (int a_ = 0; a_ < 2; a_++)
#pragma unroll
        for (int b_ = 0; b_ < 2; b_++)
#pragma unroll
            for (int c_ = 0; c_ < 4; c_++)
#pragma unroll
                for (int d_ = 0; d_ < 2; d_++)
                    acc[a_][b_][c_][d_] = (f32x4){0.f, 0.f, 0.f, 0.f};

    // ---- prologue: T0 complete + T1 {A0, B0, A1}; 3 newest half-tiles in flight
    STAGE_A(0, 0, 0); STAGE_A(0, 1, 0); STAGE_B(0, 0, 0); STAGE_B(0, 1, 0);
    STAGE_A(1, 0, 1); STAGE_B(1, 0, 1); STAGE_A(1, 1, 1);
    VM6;
    BARR;

    for (int i = 0; i < NI; ++i) {
        const int TB = 2 * i + 1, T2 = 2 * i + 2, T3 = 2 * i + 3;
        const bool s2 = T2 < NT, s3 = T3 < NT;
        bf16x8 a[4][2], b0[2][2], b1[2][2];

        LDA(0, 0, a); LDB(0, 0, b0);
        STAGE_B(1, 1, TB);
        GATE_A;
        MM(0, 0, a, b0);
        BARR;
        LDB(0, 1, b1);
        if (s2) STAGE_A(0, 0, T2);
        GATE_A;
        MM(0, 1, a, b1);
        BARR;
        LDA(0, 1, a); LDB(0, 0, b0);
        GATE_A;
        MM(1, 0, a, b0);
        BARR;
        LDB(0, 1, b1);
        if (s2) STAGE_B(0, 0, T2);
        GATE_A;
        MM(1, 1, a, b1);
        if (i < NI - 1) { VM4; } else { VM0; }
        BARR;
        LDA(1, 0, a); LDB(1, 0, b0);
        if (s2) STAGE_A(0, 1, T2);
        GATE_A;
        MM(0, 0, a, b0);
        BARR;
        LDB(1, 1, b1);
        if (s2) STAGE_B(0, 1, T2);
        if (s3) STAGE_A(1, 0, T3);
        GATE_A;
        MM(0, 1, a, b1);
        BARR;
        LDA(1, 1, a); LDB(1, 0, b0);
        GATE_A;
        MM(1, 0, a, b0);
        BARR;
        LDB(1, 1, b1);
        if (s3) { STAGE_B(1, 0, T3); STAGE_A(1, 1, T3); }
        GATE_A;
        MM(1, 1, a, b1);
        if (i < NI - 1) { VM6; }
        BARR;
    }
#undef STAGE_A
#undef STAGE_B
#undef LDA
#undef LDB
#undef MM
#undef VM0
#undef VM4
#undef VM6
#undef LGKM0
#undef SCHED0
#undef BARR
#undef GATE_A

    // ---- epilogue ----
    if (by < 8) {
        const float sc = (by < 4) ? 0.125f : 1.0f;
        float fr[2][2];
#pragma unroll
        for (int hn = 0; hn < 2; hn++)
#pragma unroll
            for (int cb = 0; cb < 2; cb++)
                fr[hn][cb] = __expf(-(float)((hn * 32 + cb * 16 + l16) & ~1) *
                                    (9.210340371976184f / 64.0f));
        const float par = (l16 & 1) ? 1.f : -1.f;
#pragma unroll
        for (int hm = 0; hm < 2; hm++)
#pragma unroll
            for (int rb = 0; rb < 4; rb++)
#pragma unroll
                for (int r = 0; r < 4; r++) {
                    int row = m0 + wm * 128 + hm * 64 + rb * 16 + quad * 4 + r;
                    float p = (float)pos[row & (SEQ_LEN - 1)];
#pragma unroll
                    for (int hn = 0; hn < 2; hn++)
#pragma unroll
                        for (int cb = 0; cb < 2; cb++) {
                            float sn, cs;
                            __sincosf(p * fr[hn][cb], &sn, &cs);
                            float v  = acc[hm][hn][rb][cb][r];
                            float pt = __shfl_xor(v, 1);
                            C[(size_t)row * LDQK + n0 + wn * 64 + hn * 32 + cb * 16 + l16] =
                                __float2bfloat16((v * cs + par * pt * sn) * sc);
                        }
                }
    } else {
#pragma unroll
        for (int hm = 0; hm < 2; hm++)
#pragma unroll
            for (int rb = 0; rb < 4; rb++) {
                int row0e = m0 + wm * 128 + hm * 64 + rb * 16 + quad * 4;
                int bb = row0e >> 11, ss = row0e & (SEQ_LEN - 1);
                int ssw = (ss & ~12) | ((ss & 4) << 1) | ((ss & 8) >> 1);
#pragma unroll
                for (int hn = 0; hn < 2; hn++)
#pragma unroll
                    for (int cb = 0; cb < 2; cb++) {
                        int vcol = n0 + wn * 64 + hn * 32 + cb * 16 + l16 - 2048;
                        int hh = vcol >> 6, dd = vcol & 63;
                        ushort4 u;
                        u.x = (unsigned short)f2b(acc[hm][hn][rb][cb][0]);
                        u.y = (unsigned short)f2b(acc[hm][hn][rb][cb][1]);
                        u.z = (unsigned short)f2b(acc[hm][hn][rb][cb][2]);
                        u.w = (unsigned short)f2b(acc[hm][hn][rb][cb][3]);
                        *(ushort4*)(Vtg + ((size_t)(bb * NH + hh) * HD + dd) * SEQ_LEN + ssw) = u;
                    }
            }
    }
}

// ---------------------------------------------------------------------------
// gemm_op (out-projection): 64x128 tile, grid 512 = 2 blocks/CU.
// (Unchanged from round 11 — passing, <45 us.)
// ---------------------------------------------------------------------------
__global__ __launch_bounds__(256) void gemm_op(
    const __hip_bfloat16* __restrict__ A,
    const __hip_bfloat16* __restrict__ B,
    float* __restrict__ C) {
    __shared__ __hip_bfloat16 As[2][64 * 32];
    __shared__ __hip_bfloat16 Bs[2][128 * 32];
    const int t    = threadIdx.x;
    const int wave = t >> 6;
    const int lane = t & 63;
    const int quad = lane >> 4;
    const int l16  = lane & 15;
    const int wy = wave >> 1, wx = wave & 1;
    const int K = DM;

    const int wg = (blockIdx.x & 7) * 64 + (blockIdx.x >> 3);
    const int m0 = (wg & 63) * 64;
    const int n0 = (wg >> 6) * 128;

    const int sr  = t >> 2;
    const int scx = (t & 3) ^ (sr & 3);

    const __hip_bfloat16* Ag = A + (size_t)(m0 + sr) * K + scx * 8;
    const __hip_bfloat16* Bg = B + (size_t)(n0 + sr) * K + scx * 8;

#define OSTAGE(BUF, K0)                                                         \
    {                                                                           \
        gload_lds16(Ag + (K0), (char*)As[BUF] + t * 16);                        \
        gload_lds16(Bg + (K0), (char*)Bs[BUF] + t * 16);                        \
        gload_lds16(Bg + (size_t)64 * K + (K0), (char*)Bs[BUF] + (t + 256) * 16); \
    }

    f32x4 acc[2][4];
#pragma unroll
    for (int i = 0; i < 2; i++)
#pragma unroll
        for (int j = 0; j < 4; j++) acc[i][j] = (f32x4){0.f, 0.f, 0.f, 0.f};

    const int NT = K >> 5;
    OSTAGE(0, 0);
    __syncthreads();
    int cur = 0;
    for (int t32 = 0; t32 < NT; ++t32) {
        if (t32 + 1 < NT) OSTAGE(cur ^ 1, (t32 + 1) * 32);

        bf16x8 af[2], bfr[4];
#pragma unroll
        for (int rb = 0; rb < 2; rb++) {
            int row = wy * 32 + rb * 16 + l16;
            af[rb] = *(const bf16x8*)((const char*)As[cur] + row * 64 +
                                      ((quad ^ (row & 3)) << 4));
        }
#pragma unroll
        for (int cb = 0; cb < 4; cb++) {
            int row = wx * 64 + cb * 16 + l16;
            bfr[cb] = *(const bf16x8*)((const char*)Bs[cur] + row * 64 +
                                       ((quad ^ (row & 3)) << 4));
        }
#pragma unroll
        for (int rb = 0; rb < 2; rb++)
#pragma unroll
            for (int cb = 0; cb < 4; cb++)
                acc[rb][cb] = __builtin_amdgcn_mfma_f32_16x16x32_bf16(
                    af[rb], bfr[cb], acc[rb][cb], 0, 0, 0);

        __syncthreads();
        cur ^= 1;
    }
#undef OSTAGE

#pragma unroll
    for (int rb = 0; rb < 2; rb++)
#pragma unroll
        for (int r = 0; r < 4; r++) {
            size_t ro = (size_t)(m0 + wy * 32 + rb * 16 + quad * 4 + r) * DM;
#pragma unroll
            for (int cb = 0; cb < 4; cb++)
                C[ro + n0 + wx * 64 + cb * 16 + l16] = acc[rb][cb][r];
        }
}

// ---------------------------------------------------------------------------
// Causal MFMA flash attention — MATCHED-WEIGHT pairing edition.
// Structure identical to round 8/11 (32x32 swapped QK^T, in-register P via
// V key-bit2<->3 pre-permute, XOR-swizzled LDS, async gload_lds staging).
// Changes vs round 11:
//  (1) qt decode pairs blocks (id, id+256) — which the in-order dispatcher
//      puts on the SAME CU (512 blocks / 256 CUs, 2-block capacity) — as
//      (15,14), (13,12), ..., (1,0): both co-resident blocks run ~equal
//      trip counts, so heavy CUs keep 2 waves/SIMD in decorrelated barrier
//      domains for the WHOLE kernel. Round 11's (15-c, c) pairing let the
//      light block die after 2 trips -> the heavy block ran 1 wave/SIMD
//      with all per-trip latency exposed (measured 11% occupancy,
//      invariant 1.4 us/trip across 4 redesigns).
//      Decode stays bijective on qt in [0,16) per (b,h); id%8 = hb%8 keeps
//      XCD locality.
//  (2) PV accumulators split 2-way (o0a/o0b, o1a/o1b over kc pairs):
//      halves the in-trip MFMA dependency chain; merged in the epilogue.
// ---------------------------------------------------------------------------
__global__ __launch_bounds__(256, 2) void attn_kernel(
    const __hip_bfloat16* __restrict__ QK,
    const __hip_bfloat16* __restrict__ Vtg,
    __hip_bfloat16* __restrict__ O) {
    __shared__ __hip_bfloat16 Ks[2][64 * 64];  // [buf][key][d]  XOR-swizzled
    __shared__ __hip_bfloat16 Vs[2][64 * 64];  // [buf][d][key'] XOR-swizzled

    const int t    = threadIdx.x;
    const int wave = t >> 6;
    const int lane = t & 63;
    const int l5   = lane & 31;
    const int hi   = lane >> 5;
    const int id   = blockIdx.x;
    const int qtc  = id >> 5;
    const int hb   = id & 31;
    const int h    = hb & 15;
    const int b    = hb >> 4;
    // matched-weight pairing: ids i and i+256 get adjacent qt sizes
    const int qt   = (qtc < 8) ? (15 - 2 * qtc) : (14 - 2 * (qtc - 8));

    const int row0 = qt * 128 + wave * 32;
    const int ktd  = (row0 + 31) >> 6;
    const int KTM  = 2 * qt + 1;

    const int sr  = t >> 3;
    const int scx = (t & 7) ^ (sr & 7);

    const __hip_bfloat16* kbase = QK + (size_t)(b * SEQ_LEN) * LDQK + DM + h * HD;
    const __hip_bfloat16* vbase = Vtg + (size_t)((b * NH + h) * HD) * SEQ_LEN;

    bf16x8 qf[4];
    {
        const __hip_bfloat16* qp =
            QK + (size_t)(b * SEQ_LEN + row0 + l5) * LDQK + h * HD + hi * 8;
#pragma unroll
        for (int dc = 0; dc < 4; dc++) qf[dc] = *(const bf16x8*)(qp + dc * 16);
    }

    f32x16 o0a, o0b, o1a, o1b;
#pragma unroll
    for (int i = 0; i < 16; i++) { o0a[i] = 0.f; o0b[i] = 0.f; o1a[i] = 0.f; o1b[i] = 0.f; }
    float l_acc = 0.f;

#define STAGE(BUF, KT)                                                          \
    {                                                                           \
        gload_lds16(kbase + (size_t)((KT) * 64 + sr) * LDQK + scx * 8,          \
                    (char*)&Ks[BUF][0] + t * 16);                               \
        gload_lds16(kbase + (size_t)((KT) * 64 + sr + 32) * LDQK + scx * 8,     \
                    (char*)&Ks[BUF][0] + (t + 256) * 16);                       \
        gload_lds16(vbase + (size_t)sr * SEQ_LEN + (KT) * 64 + scx * 8,         \
                    (char*)&Vs[BUF][0] + t * 16);                               \
        gload_lds16(vbase + (size_t)(sr + 32) * SEQ_LEN + (KT) * 64 + scx * 8,  \
                    (char*)&Vs[BUF][0] + (t + 256) * 16);                       \
    }

#define LFRAG(BASE, ROW, CH)                                                    \
    (*(const bf16x8*)((const char*)(BASE) + (ROW) * 128 + ((((CH) ^ ((ROW) & 7))) << 4)))

#define MKPA(S, PA0, PA1)                                                       \
    {                                                                           \
        float p_[16];                                                           \
        _Pragma("unroll") for (int r = 0; r < 16; r++) {                        \
            p_[r] = __expf((S)[r]);                                             \
            l_acc += p_[r];                                                     \
        }                                                                       \
        _Pragma("unroll") for (int j = 0; j < 8; j++) {                         \
            PA0[j] = f2b(p_[j]);                                                \
            PA1[j] = f2b(p_[8 + j]);                                            \
        }                                                                       \
    }

#define TRIP(BUF, KT)                                                           \
    {                                                                           \
        f32x16 s0, s1;                                                          \
        _Pragma("unroll") for (int i = 0; i < 16; i++) { s0[i] = 0.f; s1[i] = 0.f; } \
        __builtin_amdgcn_s_setprio(1);                                          \
        _Pragma("unroll") for (int dc = 0; dc < 4; dc++) {                      \
            bf16x8 k0f = LFRAG(Ks[BUF], l5, dc * 2 + hi);                       \
            bf16x8 k1f = LFRAG(Ks[BUF], 32 + l5, dc * 2 + hi);                  \
            s0 = __builtin_amdgcn_mfma_f32_32x32x16_bf16(k0f, qf[dc], s0, 0, 0, 0); \
            s1 = __builtin_amdgcn_mfma_f32_32x32x16_bf16(k1f, qf[dc], s1, 0, 0, 0); \
        }                                                                       \
        __builtin_amdgcn_s_setprio(0);                                          \
        if ((KT) == ktd) {                                                      \
            int qrow = row0 + l5;                                               \
            _Pragma("unroll") for (int r = 0; r < 16; r++) {                    \
                int key = (KT) * 64 + (r & 3) + 8 * (r >> 2) + 4 * hi;          \
                if (key > qrow) s0[r] = -1e30f;                                 \
                if (key + 32 > qrow) s1[r] = -1e30f;                            \
            }                                                                   \
        }                                                                       \
        bf16x8 pa0, pa1, pa2, pa3;                                              \
        MKPA(s0, pa0, pa1);                                                     \
        MKPA(s1, pa2, pa3);                                                     \
        __builtin_amdgcn_s_setprio(1);                                          \
        _Pragma("unroll") for (int kc = 0; kc < 2; kc++) {                      \
            bf16x8 v0f = LFRAG(Vs[BUF], l5, kc * 2 + hi);                       \
            bf16x8 v1f = LFRAG(Vs[BUF], 32 + l5, kc * 2 + hi);                  \
            bf16x8 paf = (kc == 0) ? pa0 : pa1;                                 \
            o0a = __builtin_amdgcn_mfma_f32_32x32x16_bf16(paf, v0f, o0a, 0, 0, 0); \
            o1a = __builtin_amdgcn_mfma_f32_32x32x16_bf16(paf, v1f, o1a, 0, 0, 0); \
        }                                                                       \
        _Pragma("unroll") for (int kc = 2; kc < 4; kc++) {                      \
            bf16x8 v0f = LFRAG(Vs[BUF], l5, kc * 2 + hi);                       \
            bf16x8 v1f = LFRAG(Vs[BUF], 32 + l5, kc * 2 + hi);                  \
            bf16x8 paf = (kc == 2) ? pa2 : pa3;                                 \
            o0b = __builtin_amdgcn_mfma_f32_32x32x16_bf16(paf, v0f, o0b, 0, 0, 0); \
            o1b = __builtin_amdgcn_mfma_f32_32x32x16_bf16(paf, v1f, o1b, 0, 0, 0); \
        }                                                                       \
        __builtin_amdgcn_s_setprio(0);                                          \
    }

    STAGE(0, 0);
    for (int kt = 0; kt <= KTM; ++kt) {
        const int buf = kt & 1;
        __syncthreads();
        if (kt < KTM) STAGE(buf ^ 1, kt + 1);
        if (kt <= ktd) TRIP(buf, kt);
    }

    l_acc += __shfl_xor(l_acc, 32);
    float inv = 1.0f / l_acc;
#pragma unroll
    for (int r = 0; r < 16; r++) {
        int crow  = (r & 3) + 8 * (r >> 2) + 4 * hi;
        float invr = __shfl(inv, crow);
        size_t ro = (size_t)(b * SEQ_LEN + row0 + crow) * DM + h * HD;
        O[ro + l5]      = __float2bfloat16((o0a[r] + o0b[r]) * invr);
        O[ro + 32 + l5] = __float2bfloat16((o1a[r] + o1b[r]) * invr);
    }
#undef STAGE
#undef LFRAG
#undef MKPA
#undef TRIP
}

// ---------------------------------------------------------------------------
// Workspace (40 MiB of 48):
//   [0,8)    xb [4096x1024] bf16, reused as Ab (attn output)
//   [8,14)   Wqkvb [3072x1024] bf16
//   [14,16)  Wob [1024x1024] bf16
//   [16,32)  QKb [4096x2048] bf16 (Q roped+scaled, K roped — fused in GEMM)
//   [32,40)  Vtg [2][16][64][2048] bf16 (key bits 2<->3 swapped layout)
// ---------------------------------------------------------------------------
extern "C" void kernel_launch(void* const* d_in, const int* in_sizes, int n_in,
                              void* d_out, int out_size, void* d_ws, size_t ws_size,
                              hipStream_t stream) {
    const float* x  = (const float*)d_in[0];
    const float* Wq = (const float*)d_in[1];
    const float* Wk = (const float*)d_in[2];
    const float* Wv = (const float*)d_in[3];
    const float* Wo = (const float*)d_in[4];
    const int* pos = (const int*)d_in[6];
    float* out = (float*)d_out;

    char* w = (char*)d_ws;
    const size_t MiB = 1024 * 1024;
    __hip_bfloat16* xb    = (__hip_bfloat16*)(w + 0 * MiB);
    __hip_bfloat16* Ab    = (__hip_bfloat16*)(w + 0 * MiB);  // reuse after QKV gemm
    __hip_bfloat16* Wqkvb = (__hip_bfloat16*)(w + 8 * MiB);
    __hip_bfloat16* Wob   = (__hip_bfloat16*)(w + 14 * MiB);
    __hip_bfloat16* QKb   = (__hip_bfloat16*)(w + 16 * MiB);
    __hip_bfloat16* Vtg   = (__hip_bfloat16*)(w + 32 * MiB);

    cvt_all<<<8192, 256, 0, stream>>>(x, Wq, Wk, Wv, Wo, xb, Wqkvb, Wob);

    // QKV projection: 256^2 8-phase dual-barrier counted-vmcnt GEMM
    gemm256_qkv<<<192, 512, 0, stream>>>(xb, Wqkvb, QKb, Vtg, pos);

    attn_kernel<<<512, 256, 0, stream>>>(QKb, Vtg, Ab);

    // out-projection: 64x128-tile GEMM, grid 512 = 2 blocks/CU
    gemm_op<<<512, 256, 0, stream>>>(Ab, Wob, out);
}

// Round 13
// 198.230 us; speedup vs baseline: 1.0036x; 1.0036x over previous
//
#include <hip/hip_runtime.h>
#include <hip/hip_bf16.h>

#define SEQ_LEN 2048
#define NBATCH 2
#define DM 1024
#define NH 16
#define HD 64
#define NR (NBATCH * SEQ_LEN)  // 4096 rows
#define NQKV (3 * DM)          // 3072 fused QKV cols
#define LDQK 2048              // QK buffer leading dim (Q cols 0..1023, K 1024..2047)

typedef __attribute__((ext_vector_type(8))) short bf16x8;
typedef __attribute__((ext_vector_type(4))) float f32x4;
typedef __attribute__((ext_vector_type(16))) float f32x16;

__device__ __forceinline__ short f2b(float f) {
    __hip_bfloat16 h = __float2bfloat16(f);
    return *reinterpret_cast<short*>(&h);
}

// async global->LDS 16B copy
__device__ __forceinline__ void gload_lds16(const void* g, void* l) {
    __builtin_amdgcn_global_load_lds(
        (const __attribute__((address_space(1))) unsigned int*)g,
        (__attribute__((address_space(3))) unsigned int*)l, 16, 0, 0);
}

// ---------------------------------------------------------------------------
// Fused fp32->bf16 conversion for all 5 inputs in one launch.
// ---------------------------------------------------------------------------
__global__ __launch_bounds__(256) void cvt_all(
    const float* __restrict__ x,  const float* __restrict__ wq,
    const float* __restrict__ wk, const float* __restrict__ wv,
    const float* __restrict__ wo,
    __hip_bfloat16* __restrict__ xb, __hip_bfloat16* __restrict__ wqkvb,
    __hip_bfloat16* __restrict__ wob) {
    int id = blockIdx.x;
    const float* src; __hip_bfloat16* dst;
    if (id < 4096) { src = x + (size_t)id * 1024; dst = xb + (size_t)id * 1024; }
    else {
        int k = id - 4096, seg = k >> 10;
        size_t off = (size_t)(k & 1023) * 1024;
        if      (seg == 0) { src = wq + off; dst = wqkvb + off; }
        else if (seg == 1) { src = wk + off; dst = wqkvb + (1u << 20) + off; }
        else if (seg == 2) { src = wv + off; dst = wqkvb + (2u << 20) + off; }
        else               { src = wo + off; dst = wob + off; }
    }
    int i = threadIdx.x * 4;
    float4 v = *(const float4*)(src + i);
    dst[i + 0] = __float2bfloat16(v.x);
    dst[i + 1] = __float2bfloat16(v.y);
    dst[i + 2] = __float2bfloat16(v.z);
    dst[i + 3] = __float2bfloat16(v.w);
}

// ---------------------------------------------------------------------------
// gemm_qkv: QKb/Vtg = xb @ Wqkvb^T with fused RoPE + V-transpose.
// 256x192 tile -> grid 16x16 = 256 blocks = 1/CU = 100% CU coverage (the
// old 256x256 grid of 192 blocks idled 25% of the chip — a hard ceiling on
// the biggest kernel). 8 waves (2M x 4N), per-wave output 128x48 (3 cb
// frags). The 8-phase dual-barrier counted-vmcnt skeleton is an ISOMORPH of
// the round-8 verified schedule: B splits into B01 (cb 0-1, 128 local rows,
// read p0/p2 — r8's "B0" role) and B2 (cb 2, 64 rows, read p1/p3 — "B1"
// role); A regions unchanged. Region-read schedule identical to r8 => r8's
// race-verified stage placement transfers verbatim. Per tile 7 gloads
// (A0:2 A1:2 B01:2 B2:1). vmcnt audit (steady state, oldest->newest):
//  entering p0: TB.{A0,B01,A1} in flight (6).
//  p0 stages TB.B2 (+1=7), p1 T2.A0 (+2=9), p3 T2.B01 (+2=11)
//   -> VM4 @p3 end retires oldest 7 = all of TB  => TB resident for p4. ✓
//  p4 T2.A1 (+2=6), p5 T2.B2+T3.A0 (+3=9), p7 T3.B01+T3.A1 (+4=13)
//   -> VM6 @p7 end retires oldest 7 = all of T2  => T2 resident for p0. ✓
// Last iter: p3 uses VM0 (drains TB.B2 etc). Swizzle: 16B-chunk XOR by
// (local row & 7) on pre-swizzled global source + ds_read; all read rows
// are ≡ l16 (mod 8) per region, stage rows ≡ t>>3 (mod 8) — consistent.
// Epilogue: per-frag col base (16-aligned) selects RoPE path (col<2048,
// Q scale 0.125 iff col<1024) or V path (transposed store into
// Vtg[b][h][d][s'] with key bits 2<->3 swapped).
// ---------------------------------------------------------------------------
__global__ __launch_bounds__(512) void gemm_qkv(
    const __hip_bfloat16* __restrict__ A,
    const __hip_bfloat16* __restrict__ B,
    __hip_bfloat16* __restrict__ C,
    __hip_bfloat16* __restrict__ Vtg,
    const int* __restrict__ pos) {
    __shared__ __hip_bfloat16 As[2][2][128 * 64];   // [buf][hm] 128 rows x 64 cols
    __shared__ __hip_bfloat16 Bs01[2][128 * 64];    // [buf] rows (r%48)<32
    __shared__ __hip_bfloat16 Bs2[2][64 * 64];      // [buf] rows (r%48)>=32

    const int t    = threadIdx.x;
    const int wave = t >> 6;        // 0..7
    const int wm   = wave >> 2;     // 0..1 (M half)
    const int wn   = wave & 3;      // 0..3 (N quarter, 48 cols each)
    const int lane = t & 63;
    const int quad = lane >> 4;
    const int l16  = lane & 15;
    const int K    = DM;            // 1024
    const int NT   = K >> 6;        // 16 K-tiles
    const int NI   = K >> 7;        // 8 iterations

    // XCD-chunked bijective decode (256 blocks, 32/XCD)
    const int wg = (blockIdx.x & 7) * 32 + (blockIdx.x >> 3);
    const int bx = wg & 15;         // M/256 = 16
    const int by = wg >> 4;         // NQKV/192 = 16
    const int m0 = bx * 256, n0 = by * 192;

    const int t16  = t * 16;
    const int scx8 = ((t & 7) ^ ((t >> 3) & 7)) * 8;  // pre-swizzled chunk
    const int srA  = t >> 3;                           // A local row (g=0)
    // B01: thread covers local rows t>>3 and (t>>3)+64; global = j*48+(lr&31)
    const int gB01 = (((t >> 3) >> 5) * 48) + ((t >> 3) & 31);
    // B2: local row t>>3; global = j*48 + 32 + (lr&15)
    const int gB2  = (((t >> 3) >> 4) * 48) + 32 + ((t >> 3) & 15);

#define STAGE_A(BUF, HM, TT)                                                    \
    {                                                                           \
        const __hip_bfloat16* _s =                                              \
            A + (size_t)(m0 + (HM) * 64 + srA) * K + (TT) * 64 + scx8;          \
        gload_lds16(_s,                   (char*)As[BUF][HM] + t16);            \
        gload_lds16(_s + (size_t)128 * K, (char*)As[BUF][HM] + t16 + 8192);     \
    }
#define STAGE_B01(BUF, TT)                                                      \
    {                                                                           \
        const __hip_bfloat16* _s =                                              \
            B + (size_t)(n0 + gB01) * K + (TT) * 64 + scx8;                     \
        gload_lds16(_s,                  (char*)Bs01[BUF] + t16);               \
        gload_lds16(_s + (size_t)96 * K, (char*)Bs01[BUF] + t16 + 8192);        \
    }
#define STAGE_B2(BUF, TT)                                                       \
    {                                                                           \
        const __hip_bfloat16* _s =                                              \
            B + (size_t)(n0 + gB2) * K + (TT) * 64 + scx8;                      \
        gload_lds16(_s, (char*)Bs2[BUF] + t16);                                 \
    }
// A frags: local row = wm*64 + rb*16 + l16 (region g=wm half at +wm*64 rows)
#define LDA(BUF, HM, AF)                                                        \
    _Pragma("unroll") for (int rb = 0; rb < 4; rb++)                            \
    _Pragma("unroll") for (int kk = 0; kk < 2; kk++)                            \
        AF[rb][kk] = *(const bf16x8*)((const char*)As[BUF][HM] +                \
            (wm * 64 + rb * 16 + l16) * 128 + (((kk * 4 + quad) ^ (l16 & 7)) << 4));
// B01 frags: local row = wn*32 + cb*16 + l16 (cb 0..1)
#define LDB01(BUF, BF)                                                          \
    _Pragma("unroll") for (int cb = 0; cb < 2; cb++)                            \
    _Pragma("unroll") for (int kk = 0; kk < 2; kk++)                            \
        BF[cb][kk] = *(const bf16x8*)((const char*)Bs01[BUF] +                  \
            (wn * 32 + cb * 16 + l16) * 128 + (((kk * 4 + quad) ^ (l16 & 7)) << 4));
// B2 frags: local row = wn*16 + l16
#define LDB2(BUF, BF)                                                           \
    _Pragma("unroll") for (int kk = 0; kk < 2; kk++)                            \
        BF[kk] = *(const bf16x8*)((const char*)Bs2[BUF] +                       \
            (wn * 16 + l16) * 128 + (((kk * 4 + quad) ^ (l16 & 7)) << 4));
#define MM16(HM, AF, BF)                                                        \
    {                                                                           \
        __builtin_amdgcn_s_setprio(1);                                          \
        _Pragma("unroll") for (int rb = 0; rb < 4; rb++)                        \
        _Pragma("unroll") for (int cb = 0; cb < 2; cb++) {                      \
            acc[HM][cb][rb] = __builtin_amdgcn_mfma_f32_16x16x32_bf16(          \
                AF[rb][0], BF[cb][0], acc[HM][cb][rb], 0, 0, 0);                \
            acc[HM][cb][rb] = __builtin_amdgcn_mfma_f32_16x16x32_bf16(          \
                AF[rb][1], BF[cb][1], acc[HM][cb][rb], 0, 0, 0);                \
        }                                                                       \
        __builtin_amdgcn_s_setprio(0);                                          \
    }
#define MM8(HM, AF, BF)                                                         \
    {                                                                           \
        __builtin_amdgcn_s_setprio(1);                                          \
        _Pragma("unroll") for (int rb = 0; rb < 4; rb++) {                      \
            acc[HM][2][rb] = __builtin_amdgcn_mfma_f32_16x16x32_bf16(           \
                AF[rb][0], BF[0], acc[HM][2][rb], 0, 0, 0);                     \
            acc[HM][2][rb] = __builtin_amdgcn_mfma_f32_16x16x32_bf16(           \
                AF[rb][1], BF[1], acc[HM][2][rb], 0, 0, 0);                     \
        }                                                                       \
        __builtin_amdgcn_s_setprio(0);                                          \
    }
#define VM0 asm volatile("s_waitcnt vmcnt(0)" ::: "memory")
#define VM4 asm volatile("s_waitcnt vmcnt(4)" ::: "memory")
#define VM6 asm volatile("s_waitcnt vmcnt(6)" ::: "memory")
#define LGKM0 asm volatile("s_waitcnt lgkmcnt(0)" ::: "memory")
#define SCHED0 __builtin_amdgcn_sched_barrier(0)
#define BARR __builtin_amdgcn_s_barrier()
#define GATE_A SCHED0; BARR; LGKM0; SCHED0

    f32x4 acc[2][3][4];
#pragma unroll
    for (int a_ = 0; a_ < 2; a_++)
#pragma unroll
        for (int b_ = 0; b_ < 3; b_++)
#pragma unroll
            for (int c_ = 0; c_ < 4; c_++)
                acc[a_][b_][c_] = (f32x4){0.f, 0.f, 0.f, 0.f};

    // ---- prologue: T0 complete (7) + T1 {A0, B01, A1} (6) in flight
    STAGE_A(0, 0, 0); STAGE_A(0, 1, 0); STAGE_B01(0, 0); STAGE_B2(0, 0);
    STAGE_A(1, 0, 1); STAGE_B01(1, 1); STAGE_A(1, 1, 1);
    VM6;   // retires T0's 7; T1's 6 may remain in flight
    BARR;

    for (int i = 0; i < NI; ++i) {
        const int TB = 2 * i + 1, T2 = 2 * i + 2, T3 = 2 * i + 3;
        const bool s2 = T2 < NT, s3 = T3 < NT;
        bf16x8 a[4][2], b01[2][2], b2[2];

        // p0 (h0,cb01,buf0): stage TB.B2 (Bs2[1] last read prev p7)
        LDA(0, 0, a); LDB01(0, b01);
        STAGE_B2(1, TB);
        GATE_A;
        MM16(0, a, b01);
        BARR;
        // p1 (h0,cb2,buf0): stage T2.A0 (As[0][0] last read p0)
        LDB2(0, b2);
        if (s2) STAGE_A(0, 0, T2);
        GATE_A;
        MM8(0, a, b2);
        BARR;
        // p2 (h1,cb01,buf0)
        LDA(0, 1, a); LDB01(0, b01);
        GATE_A;
        MM16(1, a, b01);
        BARR;
        // p3 (h1,cb2,buf0): stage T2.B01 (Bs01[0] last read p2); TB checkpoint
        LDB2(0, b2);
        if (s2) STAGE_B01(0, T2);
        GATE_A;
        MM8(1, a, b2);
        if (i < NI - 1) { VM4; } else { VM0; }
        BARR;
        // p4 (h0,cb01,buf1): stage T2.A1 (As[0][1] last read p3)
        LDA(1, 0, a); LDB01(1, b01);
        if (s2) STAGE_A(0, 1, T2);
        GATE_A;
        MM16(0, a, b01);
        BARR;
        // p5 (h0,cb2,buf1): stage T2.B2 (Bs2[0] last read p3) + T3.A0 (As[1][0] last read p4)
        LDB2(1, b2);
        if (s2) STAGE_B2(0, T2);
        if (s3) STAGE_A(1, 0, T3);
        GATE_A;
        MM8(0, a, b2);
        BARR;
        // p6 (h1,cb01,buf1)
        LDA(1, 1, a); LDB01(1, b01);
        GATE_A;
        MM16(1, a, b01);
        BARR;
        // p7 (h1,cb2,buf1): stage T3.B01 + T3.A1 (both last read p6); T2 checkpoint
        LDB2(1, b2);
        if (s3) { STAGE_B01(1, T3); STAGE_A(1, 1, T3); }
        GATE_A;
        MM8(1, a, b2);
        if (i < NI - 1) { VM6; }
        BARR;
    }
#undef STAGE_A
#undef STAGE_B01
#undef STAGE_B2
#undef LDA
#undef LDB01
#undef LDB2
#undef MM16
#undef MM8
#undef VM0
#undef VM4
#undef VM6
#undef LGKM0
#undef SCHED0
#undef BARR
#undef GATE_A

    // ---- epilogue: per-frag Q/K (RoPE) or V (transposed) path ----
    const float RC = 9.210340371976184f / 64.0f;
    float fr[3], sc[3];
    bool isv[3];
#pragma unroll
    for (int cb = 0; cb < 3; cb++) {
        int cbase = n0 + wn * 48 + cb * 16;         // 16-aligned frag col base
        isv[cb] = cbase >= 2048;
        sc[cb]  = (cbase < 1024) ? 0.125f : 1.0f;
        fr[cb]  = __expf(-(float)(((cbase + l16) & 63) & ~1) * RC);
    }
    const float par = (l16 & 1) ? 1.f : -1.f;
#pragma unroll
    for (int hm = 0; hm < 2; hm++)
#pragma unroll
        for (int rb = 0; rb < 4; rb++) {
            int rbase = m0 + wm * 128 + hm * 64 + rb * 16 + quad * 4;
            int bb = rbase >> 11, ss = rbase & (SEQ_LEN - 1);
            int ssw = (ss & ~12) | ((ss & 4) << 1) | ((ss & 8) >> 1);
#pragma unroll
            for (int cb = 0; cb < 3; cb++) {
                if (!isv[cb]) {
#pragma unroll
                    for (int r = 0; r < 4; r++) {
                        int row = rbase + r;
                        float p = (float)pos[row & (SEQ_LEN - 1)];
                        float sn, cs;
                        __sincosf(p * fr[cb], &sn, &cs);
                        float v  = acc[hm][cb][rb][r];
                        float pt = __shfl_xor(v, 1);
                        C[(size_t)row * LDQK + n0 + wn * 48 + cb * 16 + l16] =
                            __float2bfloat16((v * cs + par * pt * sn) * sc[cb]);
                    }
                } else {
                    int vc = n0 + wn * 48 + cb * 16 + l16 - 2048;
                    int hh = vc >> 6, dd = vc & 63;
                    ushort4 u;
                    u.x = (unsigned short)f2b(acc[hm][cb][rb][0]);
                    u.y = (unsigned short)f2b(acc[hm][cb][rb][1]);
                    u.z = (unsigned short)f2b(acc[hm][cb][rb][2]);
                    u.w = (unsigned short)f2b(acc[hm][cb][rb][3]);
                    *(ushort4*)(Vtg + ((size_t)(bb * NH + hh) * HD + dd) * SEQ_LEN + ssw) = u;
                }
            }
        }
}

// ---------------------------------------------------------------------------
// gemm_op (out-projection): 64x128 tile, grid 512 = 2 blocks/CU.
// (Unchanged from round 11 — passing.)
// ---------------------------------------------------------------------------
__global__ __launch_bounds__(256) void gemm_op(
    const __hip_bfloat16* __restrict__ A,
    const __hip_bfloat16* __restrict__ B,
    float* __restrict__ C) {
    __shared__ __hip_bfloat16 As[2][64 * 32];
    __shared__ __hip_bfloat16 Bs[2][128 * 32];
    const int t    = threadIdx.x;
    const int wave = t >> 6;
    const int lane = t & 63;
    const int quad = lane >> 4;
    const int l16  = lane & 15;
    const int wy = wave >> 1, wx = wave & 1;
    const int K = DM;

    const int wg = (blockIdx.x & 7) * 64 + (blockIdx.x >> 3);
    const int m0 = (wg & 63) * 64;
    const int n0 = (wg >> 6) * 128;

    const int sr  = t >> 2;
    const int scx = (t & 3) ^ (sr & 3);

    const __hip_bfloat16* Ag = A + (size_t)(m0 + sr) * K + scx * 8;
    const __hip_bfloat16* Bg = B + (size_t)(n0 + sr) * K + scx * 8;

#define OSTAGE(BUF, K0)                                                         \
    {                                                                           \
        gload_lds16(Ag + (K0), (char*)As[BUF] + t * 16);                        \
        gload_lds16(Bg + (K0), (char*)Bs[BUF] + t * 16);                        \
        gload_lds16(Bg + (size_t)64 * K + (K0), (char*)Bs[BUF] + (t + 256) * 16); \
    }

    f32x4 acc[2][4];
#pragma unroll
    for (int i = 0; i < 2; i++)
#pragma unroll
        for (int j = 0; j < 4; j++) acc[i][j] = (f32x4){0.f, 0.f, 0.f, 0.f};

    const int NT = K >> 5;
    OSTAGE(0, 0);
    __syncthreads();
    int cur = 0;
    for (int t32 = 0; t32 < NT; ++t32) {
        if (t32 + 1 < NT) OSTAGE(cur ^ 1, (t32 + 1) * 32);

        bf16x8 af[2], bfr[4];
#pragma unroll
        for (int rb = 0; rb < 2; rb++) {
            int row = wy * 32 + rb * 16 + l16;
            af[rb] = *(const bf16x8*)((const char*)As[cur] + row * 64 +
                                      ((quad ^ (row & 3)) << 4));
        }
#pragma unroll
        for (int cb = 0; cb < 4; cb++) {
            int row = wx * 64 + cb * 16 + l16;
            bfr[cb] = *(const bf16x8*)((const char*)Bs[cur] + row * 64 +
                                       ((quad ^ (row & 3)) << 4));
        }
#pragma unroll
        for (int rb = 0; rb < 2; rb++)
#pragma unroll
            for (int cb = 0; cb < 4; cb++)
                acc[rb][cb] = __builtin_amdgcn_mfma_f32_16x16x32_bf16(
                    af[rb], bfr[cb], acc[rb][cb], 0, 0, 0);

        __syncthreads();
        cur ^= 1;
    }
#undef OSTAGE

#pragma unroll
    for (int rb = 0; rb < 2; rb++)
#pragma unroll
        for (int r = 0; r < 4; r++) {
            size_t ro = (size_t)(m0 + wy * 32 + rb * 16 + quad * 4 + r) * DM;
#pragma unroll
            for (int cb = 0; cb < 4; cb++)
                C[ro + n0 + wx * 64 + cb * 16 + l16] = acc[rb][cb][r];
        }
}

// ---------------------------------------------------------------------------
// Causal MFMA flash attention — matched-weight pairing + split PV acc.
// (Unchanged from round 12 — passing.)
// ---------------------------------------------------------------------------
__global__ __launch_bounds__(256, 2) void attn_kernel(
    const __hip_bfloat16* __restrict__ QK,
    const __hip_bfloat16* __restrict__ Vtg,
    __hip_bfloat16* __restrict__ O) {
    __shared__ __hip_bfloat16 Ks[2][64 * 64];  // [buf][key][d]  XOR-swizzled
    __shared__ __hip_bfloat16 Vs[2][64 * 64];  // [buf][d][key'] XOR-swizzled

    const int t    = threadIdx.x;
    const int wave = t >> 6;
    const int lane = t & 63;
    const int l5   = lane & 31;
    const int hi   = lane >> 5;
    const int id   = blockIdx.x;
    const int qtc  = id >> 5;
    const int hb   = id & 31;
    const int h    = hb & 15;
    const int b    = hb >> 4;
    // matched-weight pairing: ids i and i+256 get adjacent qt sizes
    const int qt   = (qtc < 8) ? (15 - 2 * qtc) : (14 - 2 * (qtc - 8));

    const int row0 = qt * 128 + wave * 32;
    const int ktd  = (row0 + 31) >> 6;
    const int KTM  = 2 * qt + 1;

    const int sr  = t >> 3;
    const int scx = (t & 7) ^ (sr & 7);

    const __hip_bfloat16* kbase = QK + (size_t)(b * SEQ_LEN) * LDQK + DM + h * HD;
    const __hip_bfloat16* vbase = Vtg + (size_t)((b * NH + h) * HD) * SEQ_LEN;

    bf16x8 qf[4];
    {
        const __hip_bfloat16* qp =
            QK + (size_t)(b * SEQ_LEN + row0 + l5) * LDQK + h * HD + hi * 8;
#pragma unroll
        for (int dc = 0; dc < 4; dc++) qf[dc] = *(const bf16x8*)(qp + dc * 16);
    }

    f32x16 o0a, o0b, o1a, o1b;
#pragma unroll
    for (int i = 0; i < 16; i++) { o0a[i] = 0.f; o0b[i] = 0.f; o1a[i] = 0.f; o1b[i] = 0.f; }
    float l_acc = 0.f;

#define STAGE(BUF, KT)                                                          \
    {                                                                           \
        gload_lds16(kbase + (size_t)((KT) * 64 + sr) * LDQK + scx * 8,          \
                    (char*)&Ks[BUF][0] + t * 16);                               \
        gload_lds16(kbase + (size_t)((KT) * 64 + sr + 32) * LDQK + scx * 8,     \
                    (char*)&Ks[BUF][0] + (t + 256) * 16);                       \
        gload_lds16(vbase + (size_t)sr * SEQ_LEN + (KT) * 64 + scx * 8,         \
                    (char*)&Vs[BUF][0] + t * 16);                               \
        gload_lds16(vbase + (size_t)(sr + 32) * SEQ_LEN + (KT) * 64 + scx * 8,  \
                    (char*)&Vs[BUF][0] + (t + 256) * 16);                       \
    }

#define LFRAG(BASE, ROW, CH)                                                    \
    (*(const bf16x8*)((const char*)(BASE) + (ROW) * 128 + ((((CH) ^ ((ROW) & 7))) << 4)))

#define MKPA(S, PA0, PA1)                                                       \
    {                                                                           \
        float p_[16];                                                           \
        _Pragma("unroll") for (int r = 0; r < 16; r++) {                        \
            p_[r] = __expf((S)[r]);                                             \
            l_acc += p_[r];                                                     \
        }                                                                       \
        _Pragma("unroll") for (int j = 0; j < 8; j++) {                         \
            PA0[j] = f2b(p_[j]);                                                \
            PA1[j] = f2b(p_[8 + j]);                                            \
        }                                                                       \
    }

#define TRIP(BUF, KT)                                                           \
    {                                                                           \
        f32x16 s0, s1;                                                          \
        _Pragma("unroll") for (int i = 0; i < 16; i++) { s0[i] = 0.f; s1[i] = 0.f; } \
        __builtin_amdgcn_s_setprio(1);                                          \
        _Pragma("unroll") for (int dc = 0; dc < 4; dc++) {                      \
            bf16x8 k0f = LFRAG(Ks[BUF], l5, dc * 2 + hi);                       \
            bf16x8 k1f = LFRAG(Ks[BUF], 32 + l5, dc * 2 + hi);                  \
            s0 = __builtin_amdgcn_mfma_f32_32x32x16_bf16(k0f, qf[dc], s0, 0, 0, 0); \
            s1 = __builtin_amdgcn_mfma_f32_32x32x16_bf16(k1f, qf[dc], s1, 0, 0, 0); \
        }                                                                       \
        __builtin_amdgcn_s_setprio(0);                                          \
        if ((KT) == ktd) {                                                      \
            int qrow = row0 + l5;                                               \
            _Pragma("unroll") for (int r = 0; r < 16; r++) {                    \
                int key = (KT) * 64 + (r & 3) + 8 * (r >> 2) + 4 * hi;          \
                if (key > qrow) s0[r] = -1e30f;                                 \
                if (key + 32 > qrow) s1[r] = -1e30f;                            \
            }                                                                   \
        }                                                                       \
        bf16x8 pa0, pa1, pa2, pa3;                                              \
        MKPA(s0, pa0, pa1);                                                     \
        MKPA(s1, pa2, pa3);                                                     \
        __builtin_amdgcn_s_setprio(1);                                          \
        _Pragma("unroll") for (int kc = 0; kc < 2; kc++) {                      \
            bf16x8 v0f = LFRAG(Vs[BUF], l5, kc * 2 + hi);                       \
            bf16x8 v1f = LFRAG(Vs[BUF], 32 + l5, kc * 2 + hi);                  \
            bf16x8 paf = (kc == 0) ? pa0 : pa1;                                 \
            o0a = __builtin_amdgcn_mfma_f32_32x32x16_bf16(paf, v0f, o0a, 0, 0, 0); \
            o1a = __builtin_amdgcn_mfma_f32_32x32x16_bf16(paf, v1f, o1a, 0, 0, 0); \
        }                                                                       \
        _Pragma("unroll") for (int kc = 2; kc < 4; kc++) {                      \
            bf16x8 v0f = LFRAG(Vs[BUF], l5, kc * 2 + hi);                       \
            bf16x8 v1f = LFRAG(Vs[BUF], 32 + l5, kc * 2 + hi);                  \
            bf16x8 paf = (kc == 2) ? pa2 : pa3;                                 \
            o0b = __builtin_amdgcn_mfma_f32_32x32x16_bf16(paf, v0f, o0b, 0, 0, 0); \
            o1b = __builtin_amdgcn_mfma_f32_32x32x16_bf16(paf, v1f, o1b, 0, 0, 0); \
        }                                                                       \
        __builtin_amdgcn_s_setprio(0);                                          \
    }

    STAGE(0, 0);
    for (int kt = 0; kt <= KTM; ++kt) {
        const int buf = kt & 1;
        __syncthreads();
        if (kt < KTM) STAGE(buf ^ 1, kt + 1);
        if (kt <= ktd) TRIP(buf, kt);
    }

    l_acc += __shfl_xor(l_acc, 32);
    float inv = 1.0f / l_acc;
#pragma unroll
    for (int r = 0; r < 16; r++) {
        int crow  = (r & 3) + 8 * (r >> 2) + 4 * hi;
        float invr = __shfl(inv, crow);
        size_t ro = (size_t)(b * SEQ_LEN + row0 + crow) * DM + h * HD;
        O[ro + l5]      = __float2bfloat16((o0a[r] + o0b[r]) * invr);
        O[ro + 32 + l5] = __float2bfloat16((o1a[r] + o1b[r]) * invr);
    }
#undef STAGE
#undef LFRAG
#undef MKPA
#undef TRIP
}

// ---------------------------------------------------------------------------
// Workspace (40 MiB of 48):
//   [0,8)    xb [4096x1024] bf16, reused as Ab (attn output)
//   [8,14)   Wqkvb [3072x1024] bf16
//   [14,16)  Wob [1024x1024] bf16
//   [16,32)  QKb [4096x2048] bf16 (Q roped+scaled, K roped — fused in GEMM)
//   [32,40)  Vtg [2][16][64][2048] bf16 (key bits 2<->3 swapped layout)
// ---------------------------------------------------------------------------
extern "C" void kernel_launch(void* const* d_in, const int* in_sizes, int n_in,
                              void* d_out, int out_size, void* d_ws, size_t ws_size,
                              hipStream_t stream) {
    const float* x  = (const float*)d_in[0];
    const float* Wq = (const float*)d_in[1];
    const float* Wk = (const float*)d_in[2];
    const float* Wv = (const float*)d_in[3];
    const float* Wo = (const float*)d_in[4];
    const int* pos = (const int*)d_in[6];
    float* out = (float*)d_out;

    char* w = (char*)d_ws;
    const size_t MiB = 1024 * 1024;
    __hip_bfloat16* xb    = (__hip_bfloat16*)(w + 0 * MiB);
    __hip_bfloat16* Ab    = (__hip_bfloat16*)(w + 0 * MiB);  // reuse after QKV gemm
    __hip_bfloat16* Wqkvb = (__hip_bfloat16*)(w + 8 * MiB);
    __hip_bfloat16* Wob   = (__hip_bfloat16*)(w + 14 * MiB);
    __hip_bfloat16* QKb   = (__hip_bfloat16*)(w + 16 * MiB);
    __hip_bfloat16* Vtg   = (__hip_bfloat16*)(w + 32 * MiB);

    cvt_all<<<8192, 256, 0, stream>>>(x, Wq, Wk, Wv, Wo, xb, Wqkvb, Wob);

    // QKV projection: 256x192-tile 8-phase GEMM, 256 blocks = 100% CU coverage
    gemm_qkv<<<256, 512, 0, stream>>>(xb, Wqkvb, QKb, Vtg, pos);

    attn_kernel<<<512, 256, 0, stream>>>(QKb, Vtg, Ab);

    // out-projection: 64x128-tile GEMM, grid 512 = 2 blocks/CU
    gemm_op<<<512, 256, 0, stream>>>(Ab, Wob, out);
}